// Round 17
// baseline (201.285 us; speedup 1.0000x reference)
//
#include <hip/hip_runtime.h>
#include <hip/hip_bf16.h>

// ---------------------------------------------------------------------------
// ALiBi MHA, windowed. B=2 T=2048 D=1024 H=16 d_k=64, window/2=128.
// Round 17 (base = round 15, 197.7us): the batch-0 half of the attn
// zero-fill (256MB) moves to 512 DEDICATED store-only blocks appended to the
// QKV GEMM grid (1280 blocks total). Mechanism: the GEMM phase has an
// almost idle store pipe (24MB/40us) and its blocks never barrier against
// the fill blocks -> true overlap (unlike epilogue/in-loop placements,
// rounds 5/7/8, or attn-co-resident placement, round 6). Cs is overlaid on
// As/Bs (union, 17KB LDS) to keep residency slots free for fill blocks.
// Attn keeps round-15 interleaved fill for batch-1 only (~298MB writes,
// now fully hidden under its ~78us compute).
// ---------------------------------------------------------------------------

typedef __bf16 bf16x8 __attribute__((ext_vector_type(8)));
typedef float f32x4 __attribute__((ext_vector_type(4)));

__device__ __forceinline__ float bf2f(unsigned short u) {
    union { unsigned int i; float f; } v; v.i = ((unsigned int)u) << 16; return v.f;
}
__device__ __forceinline__ unsigned short f2bf(float f) {
    union { float f; unsigned int i; } v; v.f = f;
    unsigned int r = v.i + 0x7FFFu + ((v.i >> 16) & 1u);
    return (unsigned short)(r >> 16);
}

// slice 0..3: x (4M elems) -> xb ; slice 4..7: Wq/Wk/Wv/Wo -> wb
__global__ __launch_bounds__(256) void cast_all(
    const float* __restrict__ x,
    const float* __restrict__ wq, const float* __restrict__ wk,
    const float* __restrict__ wv, const float* __restrict__ wo,
    unsigned short* __restrict__ xb, unsigned short* __restrict__ wb)
{
    const int slice = blockIdx.y;
    const int i = (blockIdx.x * 256 + threadIdx.x) * 4;
    const float* src;
    unsigned short* dst;
    if (slice < 4) {
        src = x + (size_t)slice * 1048576;
        dst = xb + (size_t)slice * 1048576;
    } else {
        const float* ws4[4] = {wq, wk, wv, wo};
        src = ws4[slice - 4];
        dst = wb + (size_t)(slice - 4) * 1048576;
    }
    const float4 v = *(const float4*)(src + i);
    ushort4 o;
    o.x = f2bf(v.x); o.y = f2bf(v.y); o.z = f2bf(v.z); o.w = f2bf(v.w);
    *(ushort4*)(dst + i) = o;
}

#define GLDS16(g, l) __builtin_amdgcn_global_load_lds(                      \
    (const __attribute__((address_space(1))) void*)(g),                     \
    (__attribute__((address_space(3))) void*)(l), 16, 0, 0)

// Blocks [0,768): QKV GEMM, C = A (MxK) * Bm^T (NxK), bf16 out, V
// transposed -> (B,H,64,T), XCD-swizzled, Cs overlaid on As/Bs (17KB LDS).
// Blocks [768,1280): pure zero-fill of batch-0's out-of-window attn region
// (one 64-row head-slab per block; no barriers -> overlaps GEMM blocks).
__global__ __launch_bounds__(256) void gemm_qkv_fill(
    const unsigned short* __restrict__ A, const unsigned short* __restrict__ Bm,
    unsigned short* __restrict__ qkv, float* __restrict__ attnbuf,
    const int* __restrict__ wptr, int M, int N, int K)
{
    __shared__ __align__(16) unsigned char smem[17408];  // max(As+Bs, Cs)
    unsigned short* As = (unsigned short*)smem;          // 128*32 = 8KB
    unsigned short* Bs = As + 4096;                      // 128*32 = 8KB
    typedef unsigned short CsRow[136];
    CsRow* Cs = (CsRow*)smem;                            // [64][136] = 17KB

    const int lin = (int)blockIdx.x;
    const int tid  = threadIdx.x;
    const int lane = tid & 63, w = tid >> 6;

    if (lin >= 768) {
        // ---- fill unit: batch-0 slab (h, tblk) out-of-window zeros ----
        const int slab = lin - 768;                      // 0..511
        const int W2f = wptr[0] >> 1;
        const int t0f = (slab & 31) * 64;
        const int sAf = (t0f - W2f) > 0 ? (t0f - W2f) : 0;
        int sEf = t0f + 64 + W2f; if (sEf > 2048) sEf = 2048;
        const size_t rowbase = (size_t)((slab >> 5) & 15) * 2048 + t0f; // b=0
        const f32x4 z4 = {0.f, 0.f, 0.f, 0.f};
        for (int i = 0; i < 16; ++i) {
            float* rp = attnbuf + (rowbase + w * 16 + i) * 2048;
            for (int c = lane * 4; c < sAf; c += 256)
                __builtin_nontemporal_store(z4, (f32x4*)(rp + c));
            for (int c = sEf + lane * 4; c < 2048; c += 256)
                __builtin_nontemporal_store(z4, (f32x4*)(rp + c));
        }
        return;
    }

    // ---- GEMM unit ----
    // bijective XCD-chunk swizzle: nwg = 768, 96 per XCD
    const int swz = (lin & 7) * 96 + (lin >> 3);
    const int bx = swz % 24, by = swz / 24;
    const int bm = by * 128, bn = bx * 128;

    const unsigned short* ga = A  + (size_t)(bm + w * 16 + (lane >> 2)) * K + (lane & 3) * 8;
    const unsigned short* gb = Bm + (size_t)(bn + w * 16 + (lane >> 2)) * K + (lane & 3) * 8;
    unsigned short* laA0 = &As[w * 512];
    unsigned short* laA1 = &As[2048 + w * 512];
    unsigned short* laB0 = &Bs[w * 512];
    unsigned short* laB1 = &Bs[2048 + w * 512];

    const int wr = w >> 1, wc = w & 1;
    const int fr = lane & 15, fq = lane >> 4;

    f32x4 acc[4][4] = {};

    for (int k0 = 0; k0 < K; k0 += 32) {
        GLDS16(ga + k0, laA0);
        GLDS16(ga + k0 + (size_t)64 * K, laA1);
        GLDS16(gb + k0, laB0);
        GLDS16(gb + k0 + (size_t)64 * K, laB1);
        __syncthreads();
        bf16x8 af[4], bfv[4];
#pragma unroll
        for (int i = 0; i < 4; ++i)
            af[i] = *(const bf16x8*)&As[(wr * 64 + i * 16 + fr) * 32 + fq * 8];
#pragma unroll
        for (int j = 0; j < 4; ++j)
            bfv[j] = *(const bf16x8*)&Bs[(wc * 64 + j * 16 + fr) * 32 + fq * 8];
#pragma unroll
        for (int i = 0; i < 4; ++i)
#pragma unroll
            for (int j = 0; j < 4; ++j)
                acc[i][j] = __builtin_amdgcn_mfma_f32_16x16x32_bf16(af[i], bfv[j], acc[i][j], 0, 0, 0);
        __syncthreads();   // also protects the As/Bs <-> Cs overlay
    }

    const int which = bn >> 10;                     // 0=Q 1=K 2=V (uniform)
#pragma unroll
    for (int half = 0; half < 2; ++half) {
        __syncthreads();
        if (which == 2) {
            if (wc == half) {
#pragma unroll
                for (int i = 0; i < 4; ++i)
#pragma unroll
                    for (int j = 0; j < 4; ++j) {
                        const int lr = wr * 64 + i * 16 + fq * 4;  // m_local
                        const int lc = j * 16 + fr;                // n within 64
#pragma unroll
                        for (int r = 0; r < 4; ++r)
                            Cs[lc][lr + r] = f2bf(acc[i][j][r]);
                    }
            }
        } else {
            if (wr == half) {
#pragma unroll
                for (int i = 0; i < 4; ++i)
#pragma unroll
                    for (int j = 0; j < 4; ++j) {
                        const int lr = i * 16 + fq * 4;            // m within 64
                        const int lc = wc * 64 + j * 16 + fr;
#pragma unroll
                        for (int r = 0; r < 4; ++r)
                            Cs[lr + r][lc] = f2bf(acc[i][j][r]);
                    }
            }
        }
        __syncthreads();
#pragma unroll
        for (int rep = 0; rep < 4; ++rep) {
            const int idx = rep * 256 + tid;
            const int row = idx >> 4;               // 0..63
            const int ch  = idx & 15;               // chunk of 8 cols
            const bf16x8 vv = *(const bf16x8*)&Cs[row][ch * 8];
            if (which == 2) {
                const int nn = bn + half * 64 + row;      // global n (dd axis)
                const int hh = (nn >> 6) & 15, dd = nn & 63;
                const int mm = bm + ch * 8;               // tt base
                const int bb = mm >> 11, tt = mm & 2047;
                *(bf16x8*)(qkv + (size_t)2 * 4194304 +
                           (((size_t)bb * 16 + hh) * 64 + dd) * 2048 + tt) = vv;
            } else {
                const int mm = bm + half * 64 + row;      // global m (token)
                const int bb = mm >> 11, tt = mm & 2047;
                const int nn = bn + ch * 8;
                const int hh = (nn >> 6) & 15, dd = nn & 63;
                *(bf16x8*)(qkv + (size_t)which * 4194304 +
                           (((size_t)bb * 16 + hh) * 2048 + tt) * 64 + dd) = vv;
            }
        }
    }
}

// 64x128-tile fp32-output GEMM (512 blocks = 2/CU, XCD-swizzled).
// Non-temporal C stores (out is write-only).
__global__ __launch_bounds__(256) void gemm_bf16_nt_out(
    const unsigned short* __restrict__ A, const unsigned short* __restrict__ Bm,
    float* __restrict__ C, int M, int N, int K)
{
    __shared__ __align__(16) unsigned short As[64 * 32];
    __shared__ __align__(16) unsigned short Bs[128 * 32];

    const int tid  = threadIdx.x;
    const int lane = tid & 63, w = tid >> 6;

    // bijective XCD swizzle: nwg = 8*64 = 512, 64 per XCD
    const int lin = (int)(blockIdx.y * gridDim.x + blockIdx.x);
    const int swz = (lin & 7) * 64 + (lin >> 3);
    const int bx = swz & 7, by = swz >> 3;
    const int bm = by * 64, bn = bx * 128;

    const unsigned short* ga = A  + (size_t)(bm + w * 16 + (lane >> 2)) * K + (lane & 3) * 8;
    const unsigned short* gb = Bm + (size_t)(bn + w * 16 + (lane >> 2)) * K + (lane & 3) * 8;
    unsigned short* laA  = &As[w * 512];
    unsigned short* laB0 = &Bs[w * 512];
    unsigned short* laB1 = &Bs[2048 + w * 512];

    const int wr = w >> 1, wc = w & 1;
    const int fr = lane & 15, fq = lane >> 4;

    f32x4 acc[2][4] = {};

    for (int k0 = 0; k0 < K; k0 += 32) {
        GLDS16(ga + k0, laA);
        GLDS16(gb + k0, laB0);
        GLDS16(gb + k0 + (size_t)64 * K, laB1);
        __syncthreads();
        bf16x8 af[2], bfv[4];
#pragma unroll
        for (int i = 0; i < 2; ++i)
            af[i] = *(const bf16x8*)&As[(wr * 32 + i * 16 + fr) * 32 + fq * 8];
#pragma unroll
        for (int j = 0; j < 4; ++j)
            bfv[j] = *(const bf16x8*)&Bs[(wc * 64 + j * 16 + fr) * 32 + fq * 8];
#pragma unroll
        for (int i = 0; i < 2; ++i)
#pragma unroll
            for (int j = 0; j < 4; ++j)
                acc[i][j] = __builtin_amdgcn_mfma_f32_16x16x32_bf16(af[i], bfv[j], acc[i][j], 0, 0, 0);
        __syncthreads();
    }

#pragma unroll
    for (int i = 0; i < 2; ++i)
#pragma unroll
        for (int j = 0; j < 4; ++j) {
            const int mb = bm + wr * 32 + i * 16 + fq * 4;
            const int n  = bn + wc * 64 + j * 16 + fr;
#pragma unroll
            for (int r = 0; r < 4; ++r)
                __builtin_nontemporal_store(acc[i][j][r], &C[(size_t)(mb + r) * N + n]);
        }
}

// MFMA attention (round-15 form). Zero-fill only for batch b==1 (batch-0
// zeros are written by gemm_qkv_fill's fill blocks, which run earlier).
#define NT_MAX 20
__global__ __launch_bounds__(256) void attn_mfma(
    const unsigned short* __restrict__ Q, const unsigned short* __restrict__ K,
    const unsigned short* __restrict__ VT, float* __restrict__ attn,
    unsigned short* __restrict__ ao, const int* __restrict__ wptr)
{
    const int T = 2048;
    __shared__ __align__(16) unsigned short Plds[4][16][328];

    const int bid = (int)blockIdx.x;
    const int swz = (bid & 7) * 128 + (bid >> 3);      // XCD-contiguous
    const int w = threadIdx.x >> 6, lane = threadIdx.x & 63;
    const int fr = lane & 15, fq = lane >> 4;

    const int tblk = swz & 31;
    const int h    = (swz >> 5) & 15;
    const int b    = swz >> 9;
    const int t0   = tblk * 64;

    const int W2 = wptr[0] >> 1;                       // 128 (mult of 16)
    const int sA = (t0 - W2) > 0 ? (t0 - W2) : 0;
    int sB = t0 + 63 + W2; if (sB > T - 1) sB = T - 1;
    const int sEnd = sB + 1;                           // 16-aligned
    const int nt  = (sEnd - sA) >> 4;                  // 12..20 tiles
    const int ncc = (nt + 1) >> 1;                     // 32-wide PV chunks

    const size_t bhT = ((size_t)b * 16 + h) * T;
    const unsigned short* Qbh  = Q  + bhT * 64;
    const unsigned short* Kbh  = K  + bhT * 64;
    const unsigned short* VTbh = VT + (((size_t)b * 16 + h) * 64) * T;

    // ---- Q fragments (16 rows x 64) ----
    bf16x8 aq0 = *(const bf16x8*)(Qbh + (size_t)(t0 + w * 16 + fr) * 64 + fq * 8);
    bf16x8 aq1 = *(const bf16x8*)(Qbh + (size_t)(t0 + w * 16 + fr) * 64 + 32 + fq * 8);

    const float slope = exp2f(-0.5f * (float)(h + 1));
    const int trow0 = t0 + w * 16 + fq * 4;

    // ---- QK^T: up to 20 tiles of 16 keys ----
    f32x4 sc[NT_MAX];
#pragma unroll
    for (int st = 0; st < NT_MAX; ++st) {
        const int sbase = sA + st * 16;
        if (sbase < sEnd) {
            const unsigned short* kb = Kbh + (size_t)(sbase + fr) * 64 + fq * 8;
            bf16x8 b0 = *(const bf16x8*)(kb);
            bf16x8 b1 = *(const bf16x8*)(kb + 32);
            f32x4 sv = {0.f, 0.f, 0.f, 0.f};
            sv = __builtin_amdgcn_mfma_f32_16x16x32_bf16(aq0, b0, sv, 0, 0, 0);
            sv = __builtin_amdgcn_mfma_f32_16x16x32_bf16(aq1, b1, sv, 0, 0, 0);
            const int scol = sbase + fr;
#pragma unroll
            for (int rr = 0; rr < 4; ++rr) {
                const int d = trow0 + rr - scol;
                const int ad = d < 0 ? -d : d;
                const float val = sv[rr] * 0.125f - slope * (float)ad;
                sc[st][rr] = (ad <= W2) ? val : -1e30f;
            }
        } else {
            sc[st] = (f32x4){-1e30f, -1e30f, -1e30f, -1e30f};
        }
    }

    // ---- zero stores for batch-1 rows only (non-temporal, early issue) ----
    if (b) {
        const f32x4 z4 = {0.f, 0.f, 0.f, 0.f};
        for (int i = 0; i < 16; ++i) {
            float* row = attn + (bhT + t0 + w * 16 + i) * T;
            for (int c = lane * 4; c < sA; c += 256)
                __builtin_nontemporal_store(z4, (f32x4*)(row + c));
            for (int c = sEnd + lane * 4; c < T; c += 256)
                __builtin_nontemporal_store(z4, (f32x4*)(row + c));
        }
    }

    // ---- softmax per row (row spread over 16 fr-lanes); stores drain ----
    float inv[4];
#pragma unroll
    for (int rr = 0; rr < 4; ++rr) {
        float m = -1e30f;
#pragma unroll
        for (int st = 0; st < NT_MAX; ++st) m = fmaxf(m, sc[st][rr]);
#pragma unroll
        for (int off = 1; off < 16; off <<= 1) m = fmaxf(m, __shfl_xor(m, off, 64));
        float s = 0.f;
#pragma unroll
        for (int st = 0; st < NT_MAX; ++st) {
            const float p = __expf(sc[st][rr] - m);
            sc[st][rr] = p;
            s += p;
        }
#pragma unroll
        for (int off = 1; off < 16; off <<= 1) s += __shfl_xor(s, off, 64);
        inv[rr] = 1.0f / s;
    }

    // ---- stage normalized probs (bf16) into per-wave LDS tile ----
#pragma unroll
    for (int st = 0; st < NT_MAX; ++st) {
        const int sbase = sA + st * 16;
        if (sbase < sEnd) {
#pragma unroll
            for (int rr = 0; rr < 4; ++rr)
                Plds[w][fq * 4 + rr][st * 16 + fr] = f2bf(sc[st][rr] * inv[rr]);
        } else {
#pragma unroll
            for (int rr = 0; rr < 4; ++rr)
                Plds[w][fq * 4 + rr][st * 16 + fr] = 0;
        }
    }

    // ---- in-window prob stores (ushort4 LDS read -> f32x4 NT store) ----
    for (int i = 0; i < 16; ++i) {
        float* row = attn + (bhT + t0 + w * 16 + i) * T;
        const unsigned short* prow = &Plds[w][i][0];
#pragma unroll
        for (int jj = 0; jj < 2; ++jj) {           // 2*64*4 = 512 >= 320 cols
            const int pc = (jj * 64 + lane) * 4;
            const int c = sA + pc;
            if (c < sEnd) {
                const ushort4 p4 = *(const ushort4*)(prow + pc);
                f32x4 v;
                v[0] = bf2f(p4.x);
                v[1] = bf2f(p4.y);
                v[2] = bf2f(p4.z);
                v[3] = bf2f(p4.w);
                __builtin_nontemporal_store(v, (f32x4*)(row + c));
            }
        }
    }

    // ---- PV (chunk-ahead pipelined): out[16q x 64d] ----
    f32x4 oacc[4] = {};
    bf16x8 vt[4], vtn[4];
#pragma unroll
    for (int j = 0; j < 4; ++j)
        vt[j] = *(const bf16x8*)(VTbh + (size_t)(j * 16 + fr) * T + sA + fq * 8);
    for (int c = 0; c < ncc; ++c) {
        const bf16x8 pa = *(const bf16x8*)&Plds[w][fr][c * 32 + fq * 8];
        if (c + 1 < ncc) {
#pragma unroll
            for (int j = 0; j < 4; ++j)
                vtn[j] = *(const bf16x8*)(VTbh + (size_t)(j * 16 + fr) * T + sA + (c + 1) * 32 + fq * 8);
        }
#pragma unroll
        for (int j = 0; j < 4; ++j)
            oacc[j] = __builtin_amdgcn_mfma_f32_16x16x32_bf16(pa, vt[j], oacc[j], 0, 0, 0);
#pragma unroll
        for (int j = 0; j < 4; ++j) vt[j] = vtn[j];
    }

    // ---- AO: restage 16x64 tile into dead Plds[w], vector stores (cached:
    //      AOb is re-read by the output GEMM) ----
#pragma unroll
    for (int j = 0; j < 4; ++j)
#pragma unroll
        for (int rr = 0; rr < 4; ++rr)
            Plds[w][fq * 4 + rr][j * 16 + fr] = f2bf(oacc[j][rr]);
#pragma unroll
    for (int s = 0; s < 2; ++s) {
        const int idx = s * 64 + lane;              // 0..127
        const int row = idx >> 3;                   // 0..15
        const int ch  = idx & 7;                    // chunk of 8 dims
        const bf16x8 vv = *(const bf16x8*)&Plds[w][row][ch * 8];
        *(bf16x8*)(ao + ((size_t)b * T + t0 + w * 16 + row) * 1024 + h * 64 + ch * 8) = vv;
    }
}

extern "C" void kernel_launch(void* const* d_in, const int* in_sizes, int n_in,
                              void* d_out, int out_size, void* d_ws, size_t ws_size,
                              hipStream_t stream)
{
    const float* x  = (const float*)d_in[0];
    const float* Wq = (const float*)d_in[1];
    const float* Wk = (const float*)d_in[2];
    const float* Wv = (const float*)d_in[3];
    const float* Wo = (const float*)d_in[4];
    const int*  win = (const int*)d_in[5];

    const int M = 4096, D = 1024;                 // M = B*T

    unsigned short* xb    = (unsigned short*)d_ws;            // 4096x1024
    unsigned short* Wqkvb = xb + (size_t)M * D;               // 3072x1024
    unsigned short* Wob   = Wqkvb + (size_t)3 * D * D;        // 1024x1024
    unsigned short* QKVb  = Wob + (size_t)D * D;              // Q,K,(V^T)
    unsigned short* AOb   = QKVb + (size_t)3 * M * D;         // 4096x1024

    float* out  = (float*)d_out;                  // (B,T,D)
    float* attn = out + (size_t)M * D;            // (B,H,T,T)

    {
        dim3 g(1024, 8);
        cast_all<<<g, 256, 0, stream>>>(x, Wq, Wk, Wv, Wo, xb, Wqkvb);
    }

    // 768 GEMM blocks + 512 batch-0 fill blocks (overlapped)
    gemm_qkv_fill<<<1280, 256, 0, stream>>>(xb, Wqkvb, QKVb, attn, win,
                                            M, 3072, D);

    attn_mfma<<<1024, 256, 0, stream>>>(
        QKVb, QKVb + (size_t)M * D, QKVb + (size_t)2 * M * D, attn, AOb, win);

    {
        dim3 g(D / 128, M / 64);                  // 8 x 64 = 512 blocks
        gemm_bf16_nt_out<<<g, 256, 0, stream>>>(AOb, Wob, out, M, D, D);
    }
}

// Round 18
// 199.947 us; speedup vs baseline: 1.0067x; 1.0067x over previous
//
#include <hip/hip_runtime.h>
#include <hip/hip_bf16.h>

// ---------------------------------------------------------------------------
// ALiBi MHA, windowed. B=2 T=2048 D=1024 H=16 d_k=64, window/2=128.
// Round 18 (base = round 15, 197.7us): retry of round-17's concept with the
// fix for its failure mode. 512 batch-0 fill blocks are INTERLEAVED into the
// QKV GEMM grid (role = lin%5: 2 fills + 3 GEMMs per group of 5) instead of
// appended at the tail -- round 17's tail placement serialized the fills
// after the GEMM (1280 blocks > 1024 residency slots). Interleaved order
// makes fills co-resident with GEMM blocks whose store pipe is ~idle.
// attn fills batch-1 only (round-15 interleave position).
// ---------------------------------------------------------------------------

typedef __bf16 bf16x8 __attribute__((ext_vector_type(8)));
typedef float f32x4 __attribute__((ext_vector_type(4)));

__device__ __forceinline__ float bf2f(unsigned short u) {
    union { unsigned int i; float f; } v; v.i = ((unsigned int)u) << 16; return v.f;
}
__device__ __forceinline__ unsigned short f2bf(float f) {
    union { float f; unsigned int i; } v; v.f = f;
    unsigned int r = v.i + 0x7FFFu + ((v.i >> 16) & 1u);
    return (unsigned short)(r >> 16);
}

// slice 0..3: x (4M elems) -> xb ; slice 4..7: Wq/Wk/Wv/Wo -> wb
__global__ __launch_bounds__(256) void cast_all(
    const float* __restrict__ x,
    const float* __restrict__ wq, const float* __restrict__ wk,
    const float* __restrict__ wv, const float* __restrict__ wo,
    unsigned short* __restrict__ xb, unsigned short* __restrict__ wb)
{
    const int slice = blockIdx.y;
    const int i = (blockIdx.x * 256 + threadIdx.x) * 4;
    const float* src;
    unsigned short* dst;
    if (slice < 4) {
        src = x + (size_t)slice * 1048576;
        dst = xb + (size_t)slice * 1048576;
    } else {
        const float* ws4[4] = {wq, wk, wv, wo};
        src = ws4[slice - 4];
        dst = wb + (size_t)(slice - 4) * 1048576;
    }
    const float4 v = *(const float4*)(src + i);
    ushort4 o;
    o.x = f2bf(v.x); o.y = f2bf(v.y); o.z = f2bf(v.z); o.w = f2bf(v.w);
    *(ushort4*)(dst + i) = o;
}

#define GLDS16(g, l) __builtin_amdgcn_global_load_lds(                      \
    (const __attribute__((address_space(1))) void*)(g),                     \
    (__attribute__((address_space(3))) void*)(l), 16, 0, 0)

// Grid 1280. role r = lin%5: r<2 -> fill unit (batch-0 out-of-window zeros,
// fillid = (lin/5)*2+r, 512 total); r>=2 -> GEMM unit (gemmid = (lin/5)*3 +
// r-2, 768 total). GEMM: C = A (MxK) * Bm^T (NxK), bf16 out, V transposed
// -> (B,H,64,T); Cs overlaid on As/Bs (17KB LDS); vector-store epilogue.
__global__ __launch_bounds__(256) void gemm_qkv_fill(
    const unsigned short* __restrict__ A, const unsigned short* __restrict__ Bm,
    unsigned short* __restrict__ qkv, float* __restrict__ attnbuf,
    const int* __restrict__ wptr, int M, int N, int K)
{
    __shared__ __align__(16) unsigned char smem[17408];  // max(As+Bs, Cs)
    unsigned short* As = (unsigned short*)smem;          // 128*32 = 8KB
    unsigned short* Bs = As + 4096;                      // 128*32 = 8KB
    typedef unsigned short CsRow[136];
    CsRow* Cs = (CsRow*)smem;                            // [64][136] = 17KB

    const int lin = (int)blockIdx.x;
    const int tid  = threadIdx.x;
    const int lane = tid & 63, w = tid >> 6;
    const int role = lin % 5;

    if (role < 2) {
        // ---- fill unit: batch-0 slab out-of-window zeros ----
        const int slab = (lin / 5) * 2 + role;           // 0..511
        const int W2f = wptr[0] >> 1;
        const int t0f = (slab & 31) * 64;
        const int sAf = (t0f - W2f) > 0 ? (t0f - W2f) : 0;
        int sEf = t0f + 64 + W2f; if (sEf > 2048) sEf = 2048;
        const size_t rowbase = (size_t)(slab >> 5) * 2048 + t0f;  // head, b=0
        const f32x4 z4 = {0.f, 0.f, 0.f, 0.f};
        for (int i = 0; i < 16; ++i) {
            float* rp = attnbuf + (rowbase + w * 16 + i) * 2048;
            for (int c = lane * 4; c < sAf; c += 256)
                __builtin_nontemporal_store(z4, (f32x4*)(rp + c));
            for (int c = sEf + lane * 4; c < 2048; c += 256)
                __builtin_nontemporal_store(z4, (f32x4*)(rp + c));
        }
        return;
    }

    // ---- GEMM unit ----
    const int gemmid = (lin / 5) * 3 + (role - 2);       // 0..767
    const int swz = (gemmid & 7) * 96 + (gemmid >> 3);   // bijective
    const int bx = swz % 24, by = swz / 24;
    const int bm = by * 128, bn = bx * 128;

    const unsigned short* ga = A  + (size_t)(bm + w * 16 + (lane >> 2)) * K + (lane & 3) * 8;
    const unsigned short* gb = Bm + (size_t)(bn + w * 16 + (lane >> 2)) * K + (lane & 3) * 8;
    unsigned short* laA0 = &As[w * 512];
    unsigned short* laA1 = &As[2048 + w * 512];
    unsigned short* laB0 = &Bs[w * 512];
    unsigned short* laB1 = &Bs[2048 + w * 512];

    const int wr = w >> 1, wc = w & 1;
    const int fr = lane & 15, fq = lane >> 4;

    f32x4 acc[4][4] = {};

    for (int k0 = 0; k0 < K; k0 += 32) {
        GLDS16(ga + k0, laA0);
        GLDS16(ga + k0 + (size_t)64 * K, laA1);
        GLDS16(gb + k0, laB0);
        GLDS16(gb + k0 + (size_t)64 * K, laB1);
        __syncthreads();
        bf16x8 af[4], bfv[4];
#pragma unroll
        for (int i = 0; i < 4; ++i)
            af[i] = *(const bf16x8*)&As[(wr * 64 + i * 16 + fr) * 32 + fq * 8];
#pragma unroll
        for (int j = 0; j < 4; ++j)
            bfv[j] = *(const bf16x8*)&Bs[(wc * 64 + j * 16 + fr) * 32 + fq * 8];
#pragma unroll
        for (int i = 0; i < 4; ++i)
#pragma unroll
            for (int j = 0; j < 4; ++j)
                acc[i][j] = __builtin_amdgcn_mfma_f32_16x16x32_bf16(af[i], bfv[j], acc[i][j], 0, 0, 0);
        __syncthreads();   // also protects the As/Bs <-> Cs overlay
    }

    const int which = bn >> 10;                     // 0=Q 1=K 2=V (uniform)
#pragma unroll
    for (int half = 0; half < 2; ++half) {
        __syncthreads();
        if (which == 2) {
            if (wc == half) {
#pragma unroll
                for (int i = 0; i < 4; ++i)
#pragma unroll
                    for (int j = 0; j < 4; ++j) {
                        const int lr = wr * 64 + i * 16 + fq * 4;  // m_local
                        const int lc = j * 16 + fr;                // n within 64
#pragma unroll
                        for (int r = 0; r < 4; ++r)
                            Cs[lc][lr + r] = f2bf(acc[i][j][r]);
                    }
            }
        } else {
            if (wr == half) {
#pragma unroll
                for (int i = 0; i < 4; ++i)
#pragma unroll
                    for (int j = 0; j < 4; ++j) {
                        const int lr = i * 16 + fq * 4;            // m within 64
                        const int lc = wc * 64 + j * 16 + fr;
#pragma unroll
                        for (int r = 0; r < 4; ++r)
                            Cs[lr + r][lc] = f2bf(acc[i][j][r]);
                    }
            }
        }
        __syncthreads();
#pragma unroll
        for (int rep = 0; rep < 4; ++rep) {
            const int idx = rep * 256 + tid;
            const int row = idx >> 4;               // 0..63
            const int ch  = idx & 15;               // chunk of 8 cols
            const bf16x8 vv = *(const bf16x8*)&Cs[row][ch * 8];
            if (which == 2) {
                const int nn = bn + half * 64 + row;      // global n (dd axis)
                const int hh = (nn >> 6) & 15, dd = nn & 63;
                const int mm = bm + ch * 8;               // tt base
                const int bb = mm >> 11, tt = mm & 2047;
                *(bf16x8*)(qkv + (size_t)2 * 4194304 +
                           (((size_t)bb * 16 + hh) * 64 + dd) * 2048 + tt) = vv;
            } else {
                const int mm = bm + half * 64 + row;      // global m (token)
                const int bb = mm >> 11, tt = mm & 2047;
                const int nn = bn + ch * 8;
                const int hh = (nn >> 6) & 15, dd = nn & 63;
                *(bf16x8*)(qkv + (size_t)which * 4194304 +
                           (((size_t)bb * 16 + hh) * 2048 + tt) * 64 + dd) = vv;
            }
        }
    }
}

// 64x128-tile fp32-output GEMM (512 blocks = 2/CU, XCD-swizzled).
// Non-temporal C stores (out is write-only).
__global__ __launch_bounds__(256) void gemm_bf16_nt_out(
    const unsigned short* __restrict__ A, const unsigned short* __restrict__ Bm,
    float* __restrict__ C, int M, int N, int K)
{
    __shared__ __align__(16) unsigned short As[64 * 32];
    __shared__ __align__(16) unsigned short Bs[128 * 32];

    const int tid  = threadIdx.x;
    const int lane = tid & 63, w = tid >> 6;

    // bijective XCD swizzle: nwg = 8*64 = 512, 64 per XCD
    const int lin = (int)(blockIdx.y * gridDim.x + blockIdx.x);
    const int swz = (lin & 7) * 64 + (lin >> 3);
    const int bx = swz & 7, by = swz >> 3;
    const int bm = by * 64, bn = bx * 128;

    const unsigned short* ga = A  + (size_t)(bm + w * 16 + (lane >> 2)) * K + (lane & 3) * 8;
    const unsigned short* gb = Bm + (size_t)(bn + w * 16 + (lane >> 2)) * K + (lane & 3) * 8;
    unsigned short* laA  = &As[w * 512];
    unsigned short* laB0 = &Bs[w * 512];
    unsigned short* laB1 = &Bs[2048 + w * 512];

    const int wr = w >> 1, wc = w & 1;
    const int fr = lane & 15, fq = lane >> 4;

    f32x4 acc[2][4] = {};

    for (int k0 = 0; k0 < K; k0 += 32) {
        GLDS16(ga + k0, laA);
        GLDS16(gb + k0, laB0);
        GLDS16(gb + k0 + (size_t)64 * K, laB1);
        __syncthreads();
        bf16x8 af[2], bfv[4];
#pragma unroll
        for (int i = 0; i < 2; ++i)
            af[i] = *(const bf16x8*)&As[(wr * 32 + i * 16 + fr) * 32 + fq * 8];
#pragma unroll
        for (int j = 0; j < 4; ++j)
            bfv[j] = *(const bf16x8*)&Bs[(wc * 64 + j * 16 + fr) * 32 + fq * 8];
#pragma unroll
        for (int i = 0; i < 2; ++i)
#pragma unroll
            for (int j = 0; j < 4; ++j)
                acc[i][j] = __builtin_amdgcn_mfma_f32_16x16x32_bf16(af[i], bfv[j], acc[i][j], 0, 0, 0);
        __syncthreads();
    }

#pragma unroll
    for (int i = 0; i < 2; ++i)
#pragma unroll
        for (int j = 0; j < 4; ++j) {
            const int mb = bm + wr * 32 + i * 16 + fq * 4;
            const int n  = bn + wc * 64 + j * 16 + fr;
#pragma unroll
            for (int r = 0; r < 4; ++r)
                __builtin_nontemporal_store(acc[i][j][r], &C[(size_t)(mb + r) * N + n]);
        }
}

// MFMA attention (round-15 form). Zero-fill only for batch b==1 (batch-0
// zeros are written by gemm_qkv_fill's interleaved fill blocks).
#define NT_MAX 20
__global__ __launch_bounds__(256) void attn_mfma(
    const unsigned short* __restrict__ Q, const unsigned short* __restrict__ K,
    const unsigned short* __restrict__ VT, float* __restrict__ attn,
    unsigned short* __restrict__ ao, const int* __restrict__ wptr)
{
    const int T = 2048;
    __shared__ __align__(16) unsigned short Plds[4][16][328];

    const int bid = (int)blockIdx.x;
    const int swz = (bid & 7) * 128 + (bid >> 3);      // XCD-contiguous
    const int w = threadIdx.x >> 6, lane = threadIdx.x & 63;
    const int fr = lane & 15, fq = lane >> 4;

    const int tblk = swz & 31;
    const int h    = (swz >> 5) & 15;
    const int b    = swz >> 9;
    const int t0   = tblk * 64;

    const int W2 = wptr[0] >> 1;                       // 128 (mult of 16)
    const int sA = (t0 - W2) > 0 ? (t0 - W2) : 0;
    int sB = t0 + 63 + W2; if (sB > T - 1) sB = T - 1;
    const int sEnd = sB + 1;                           // 16-aligned
    const int nt  = (sEnd - sA) >> 4;                  // 12..20 tiles
    const int ncc = (nt + 1) >> 1;                     // 32-wide PV chunks

    const size_t bhT = ((size_t)b * 16 + h) * T;
    const unsigned short* Qbh  = Q  + bhT * 64;
    const unsigned short* Kbh  = K  + bhT * 64;
    const unsigned short* VTbh = VT + (((size_t)b * 16 + h) * 64) * T;

    // ---- Q fragments (16 rows x 64) ----
    bf16x8 aq0 = *(const bf16x8*)(Qbh + (size_t)(t0 + w * 16 + fr) * 64 + fq * 8);
    bf16x8 aq1 = *(const bf16x8*)(Qbh + (size_t)(t0 + w * 16 + fr) * 64 + 32 + fq * 8);

    const float slope = exp2f(-0.5f * (float)(h + 1));
    const int trow0 = t0 + w * 16 + fq * 4;

    // ---- QK^T: up to 20 tiles of 16 keys ----
    f32x4 sc[NT_MAX];
#pragma unroll
    for (int st = 0; st < NT_MAX; ++st) {
        const int sbase = sA + st * 16;
        if (sbase < sEnd) {
            const unsigned short* kb = Kbh + (size_t)(sbase + fr) * 64 + fq * 8;
            bf16x8 b0 = *(const bf16x8*)(kb);
            bf16x8 b1 = *(const bf16x8*)(kb + 32);
            f32x4 sv = {0.f, 0.f, 0.f, 0.f};
            sv = __builtin_amdgcn_mfma_f32_16x16x32_bf16(aq0, b0, sv, 0, 0, 0);
            sv = __builtin_amdgcn_mfma_f32_16x16x32_bf16(aq1, b1, sv, 0, 0, 0);
            const int scol = sbase + fr;
#pragma unroll
            for (int rr = 0; rr < 4; ++rr) {
                const int d = trow0 + rr - scol;
                const int ad = d < 0 ? -d : d;
                const float val = sv[rr] * 0.125f - slope * (float)ad;
                sc[st][rr] = (ad <= W2) ? val : -1e30f;
            }
        } else {
            sc[st] = (f32x4){-1e30f, -1e30f, -1e30f, -1e30f};
        }
    }

    // ---- zero stores for batch-1 rows only (non-temporal, early issue) ----
    if (b) {
        const f32x4 z4 = {0.f, 0.f, 0.f, 0.f};
        for (int i = 0; i < 16; ++i) {
            float* row = attn + (bhT + t0 + w * 16 + i) * T;
            for (int c = lane * 4; c < sA; c += 256)
                __builtin_nontemporal_store(z4, (f32x4*)(row + c));
            for (int c = sEnd + lane * 4; c < T; c += 256)
                __builtin_nontemporal_store(z4, (f32x4*)(row + c));
        }
    }

    // ---- softmax per row (row spread over 16 fr-lanes); stores drain ----
    float inv[4];
#pragma unroll
    for (int rr = 0; rr < 4; ++rr) {
        float m = -1e30f;
#pragma unroll
        for (int st = 0; st < NT_MAX; ++st) m = fmaxf(m, sc[st][rr]);
#pragma unroll
        for (int off = 1; off < 16; off <<= 1) m = fmaxf(m, __shfl_xor(m, off, 64));
        float s = 0.f;
#pragma unroll
        for (int st = 0; st < NT_MAX; ++st) {
            const float p = __expf(sc[st][rr] - m);
            sc[st][rr] = p;
            s += p;
        }
#pragma unroll
        for (int off = 1; off < 16; off <<= 1) s += __shfl_xor(s, off, 64);
        inv[rr] = 1.0f / s;
    }

    // ---- stage normalized probs (bf16) into per-wave LDS tile ----
#pragma unroll
    for (int st = 0; st < NT_MAX; ++st) {
        const int sbase = sA + st * 16;
        if (sbase < sEnd) {
#pragma unroll
            for (int rr = 0; rr < 4; ++rr)
                Plds[w][fq * 4 + rr][st * 16 + fr] = f2bf(sc[st][rr] * inv[rr]);
        } else {
#pragma unroll
            for (int rr = 0; rr < 4; ++rr)
                Plds[w][fq * 4 + rr][st * 16 + fr] = 0;
        }
    }

    // ---- in-window prob stores (ushort4 LDS read -> f32x4 NT store) ----
    for (int i = 0; i < 16; ++i) {
        float* row = attn + (bhT + t0 + w * 16 + i) * T;
        const unsigned short* prow = &Plds[w][i][0];
#pragma unroll
        for (int jj = 0; jj < 2; ++jj) {           // 2*64*4 = 512 >= 320 cols
            const int pc = (jj * 64 + lane) * 4;
            const int c = sA + pc;
            if (c < sEnd) {
                const ushort4 p4 = *(const ushort4*)(prow + pc);
                f32x4 v;
                v[0] = bf2f(p4.x);
                v[1] = bf2f(p4.y);
                v[2] = bf2f(p4.z);
                v[3] = bf2f(p4.w);
                __builtin_nontemporal_store(v, (f32x4*)(row + c));
            }
        }
    }

    // ---- PV (chunk-ahead pipelined): out[16q x 64d] ----
    f32x4 oacc[4] = {};
    bf16x8 vt[4], vtn[4];
#pragma unroll
    for (int j = 0; j < 4; ++j)
        vt[j] = *(const bf16x8*)(VTbh + (size_t)(j * 16 + fr) * T + sA + fq * 8);
    for (int c = 0; c < ncc; ++c) {
        const bf16x8 pa = *(const bf16x8*)&Plds[w][fr][c * 32 + fq * 8];
        if (c + 1 < ncc) {
#pragma unroll
            for (int j = 0; j < 4; ++j)
                vtn[j] = *(const bf16x8*)(VTbh + (size_t)(j * 16 + fr) * T + sA + (c + 1) * 32 + fq * 8);
        }
#pragma unroll
        for (int j = 0; j < 4; ++j)
            oacc[j] = __builtin_amdgcn_mfma_f32_16x16x32_bf16(pa, vt[j], oacc[j], 0, 0, 0);
#pragma unroll
        for (int j = 0; j < 4; ++j) vt[j] = vtn[j];
    }

    // ---- AO: restage 16x64 tile into dead Plds[w], vector stores (cached:
    //      AOb is re-read by the output GEMM) ----
#pragma unroll
    for (int j = 0; j < 4; ++j)
#pragma unroll
        for (int rr = 0; rr < 4; ++rr)
            Plds[w][fq * 4 + rr][j * 16 + fr] = f2bf(oacc[j][rr]);
#pragma unroll
    for (int s = 0; s < 2; ++s) {
        const int idx = s * 64 + lane;              // 0..127
        const int row = idx >> 3;                   // 0..15
        const int ch  = idx & 7;                    // chunk of 8 dims
        const bf16x8 vv = *(const bf16x8*)&Plds[w][row][ch * 8];
        *(bf16x8*)(ao + ((size_t)b * T + t0 + w * 16 + row) * 1024 + h * 64 + ch * 8) = vv;
    }
}

extern "C" void kernel_launch(void* const* d_in, const int* in_sizes, int n_in,
                              void* d_out, int out_size, void* d_ws, size_t ws_size,
                              hipStream_t stream)
{
    const float* x  = (const float*)d_in[0];
    const float* Wq = (const float*)d_in[1];
    const float* Wk = (const float*)d_in[2];
    const float* Wv = (const float*)d_in[3];
    const float* Wo = (const float*)d_in[4];
    const int*  win = (const int*)d_in[5];

    const int M = 4096, D = 1024;                 // M = B*T

    unsigned short* xb    = (unsigned short*)d_ws;            // 4096x1024
    unsigned short* Wqkvb = xb + (size_t)M * D;               // 3072x1024
    unsigned short* Wob   = Wqkvb + (size_t)3 * D * D;        // 1024x1024
    unsigned short* QKVb  = Wob + (size_t)D * D;              // Q,K,(V^T)
    unsigned short* AOb   = QKVb + (size_t)3 * M * D;         // 4096x1024

    float* out  = (float*)d_out;                  // (B,T,D)
    float* attn = out + (size_t)M * D;            // (B,H,T,T)

    {
        dim3 g(1024, 8);
        cast_all<<<g, 256, 0, stream>>>(x, Wq, Wk, Wv, Wo, xb, Wqkvb);
    }

    // 768 GEMM blocks + 512 batch-0 fill blocks, role-interleaved
    gemm_qkv_fill<<<1280, 256, 0, stream>>>(xb, Wqkvb, QKVb, attn, win,
                                            M, 3072, D);

    attn_mfma<<<1024, 256, 0, stream>>>(
        QKVb, QKVb + (size_t)M * D, QKVb + (size_t)2 * M * D, attn, AOb, win);

    {
        dim3 g(D / 128, M / 64);                  // 8 x 64 = 512 blocks
        gemm_bf16_nt_out<<<g, 256, 0, stream>>>(AOb, Wob, out, M, D, D);
    }
}

// Round 19
// 193.051 us; speedup vs baseline: 1.0427x; 1.0357x over previous
//
#include <hip/hip_runtime.h>
#include <hip/hip_bf16.h>

// ---------------------------------------------------------------------------
// ALiBi MHA, windowed. B=2 T=2048 D=1024 H=16 d_k=64, window/2=128.
// Round 19 (base = round 15, 197.7us; rounds 16-18's experiments reverted):
// attn grid 1024 -> 512 blocks x 2 sequential units (adjacent t-slabs of the
// same head). With 3 blocks/CU residency (41KB LDS) all 512 blocks are
// co-resident from t=0: no 1.33-round dispatch tail, unit-2 compute covers
// unit-1's store drain in-wave, and adjacent slabs share 192/320 window
// columns (L2-warm K/V).
// ---------------------------------------------------------------------------

typedef __bf16 bf16x8 __attribute__((ext_vector_type(8)));
typedef float f32x4 __attribute__((ext_vector_type(4)));

__device__ __forceinline__ float bf2f(unsigned short u) {
    union { unsigned int i; float f; } v; v.i = ((unsigned int)u) << 16; return v.f;
}
__device__ __forceinline__ unsigned short f2bf(float f) {
    union { float f; unsigned int i; } v; v.f = f;
    unsigned int r = v.i + 0x7FFFu + ((v.i >> 16) & 1u);
    return (unsigned short)(r >> 16);
}

// slice 0..3: x (4M elems) -> xb ; slice 4..7: Wq/Wk/Wv/Wo -> wb
__global__ __launch_bounds__(256) void cast_all(
    const float* __restrict__ x,
    const float* __restrict__ wq, const float* __restrict__ wk,
    const float* __restrict__ wv, const float* __restrict__ wo,
    unsigned short* __restrict__ xb, unsigned short* __restrict__ wb)
{
    const int slice = blockIdx.y;
    const int i = (blockIdx.x * 256 + threadIdx.x) * 4;
    const float* src;
    unsigned short* dst;
    if (slice < 4) {
        src = x + (size_t)slice * 1048576;
        dst = xb + (size_t)slice * 1048576;
    } else {
        const float* ws4[4] = {wq, wk, wv, wo};
        src = ws4[slice - 4];
        dst = wb + (size_t)(slice - 4) * 1048576;
    }
    const float4 v = *(const float4*)(src + i);
    ushort4 o;
    o.x = f2bf(v.x); o.y = f2bf(v.y); o.z = f2bf(v.z); o.w = f2bf(v.w);
    *(ushort4*)(dst + i) = o;
}

#define GLDS16(g, l) __builtin_amdgcn_global_load_lds(                      \
    (const __attribute__((address_space(1))) void*)(g),                     \
    (__attribute__((address_space(3))) void*)(l), 16, 0, 0)

// QKV GEMM: C = A (MxK) * Bm^T (NxK); bf16 in, fp32 accum; bf16 out with
// V (n>=2048) transposed -> (B,H,64,T). XCD-chunk swizzled grid. Epilogue
// restages 64x128 halves of C through Cs -> 16-B vector stores only.
__global__ __launch_bounds__(256) void gemm_bf16_nt(
    const unsigned short* __restrict__ A, const unsigned short* __restrict__ Bm,
    unsigned short* __restrict__ qkv, int M, int N, int K)
{
    __shared__ __align__(16) unsigned short As[128 * 32];
    __shared__ __align__(16) unsigned short Bs[128 * 32];
    __shared__ __align__(16) unsigned short Cs[64][136];

    const int tid  = threadIdx.x;
    const int lane = tid & 63, w = tid >> 6;

    // bijective XCD-chunk swizzle: nwg = 24*32 = 768, 768/8 = 96 per XCD
    const int lin = (int)(blockIdx.y * gridDim.x + blockIdx.x);
    const int swz = (lin & 7) * 96 + (lin >> 3);
    const int bx = swz % 24, by = swz / 24;
    const int bm = by * 128, bn = bx * 128;

    const unsigned short* ga = A  + (size_t)(bm + w * 16 + (lane >> 2)) * K + (lane & 3) * 8;
    const unsigned short* gb = Bm + (size_t)(bn + w * 16 + (lane >> 2)) * K + (lane & 3) * 8;
    unsigned short* laA0 = &As[w * 512];
    unsigned short* laA1 = &As[2048 + w * 512];
    unsigned short* laB0 = &Bs[w * 512];
    unsigned short* laB1 = &Bs[2048 + w * 512];

    const int wr = w >> 1, wc = w & 1;
    const int fr = lane & 15, fq = lane >> 4;

    f32x4 acc[4][4] = {};

    for (int k0 = 0; k0 < K; k0 += 32) {
        GLDS16(ga + k0, laA0);
        GLDS16(ga + k0 + (size_t)64 * K, laA1);
        GLDS16(gb + k0, laB0);
        GLDS16(gb + k0 + (size_t)64 * K, laB1);
        __syncthreads();
        bf16x8 af[4], bfv[4];
#pragma unroll
        for (int i = 0; i < 4; ++i)
            af[i] = *(const bf16x8*)&As[(wr * 64 + i * 16 + fr) * 32 + fq * 8];
#pragma unroll
        for (int j = 0; j < 4; ++j)
            bfv[j] = *(const bf16x8*)&Bs[(wc * 64 + j * 16 + fr) * 32 + fq * 8];
#pragma unroll
        for (int i = 0; i < 4; ++i)
#pragma unroll
            for (int j = 0; j < 4; ++j)
                acc[i][j] = __builtin_amdgcn_mfma_f32_16x16x32_bf16(af[i], bfv[j], acc[i][j], 0, 0, 0);
        __syncthreads();
    }

    const int which = bn >> 10;                     // 0=Q 1=K 2=V (uniform)
#pragma unroll
    for (int half = 0; half < 2; ++half) {
        __syncthreads();
        if (which == 2) {
            if (wc == half) {
#pragma unroll
                for (int i = 0; i < 4; ++i)
#pragma unroll
                    for (int j = 0; j < 4; ++j) {
                        const int lr = wr * 64 + i * 16 + fq * 4;  // m_local
                        const int lc = j * 16 + fr;                // n within 64
#pragma unroll
                        for (int r = 0; r < 4; ++r)
                            Cs[lc][lr + r] = f2bf(acc[i][j][r]);
                    }
            }
        } else {
            if (wr == half) {
#pragma unroll
                for (int i = 0; i < 4; ++i)
#pragma unroll
                    for (int j = 0; j < 4; ++j) {
                        const int lr = i * 16 + fq * 4;            // m within 64
                        const int lc = wc * 64 + j * 16 + fr;
#pragma unroll
                        for (int r = 0; r < 4; ++r)
                            Cs[lr + r][lc] = f2bf(acc[i][j][r]);
                    }
            }
        }
        __syncthreads();
#pragma unroll
        for (int rep = 0; rep < 4; ++rep) {
            const int idx = rep * 256 + tid;
            const int row = idx >> 4;               // 0..63
            const int ch  = idx & 15;               // chunk of 8 cols
            const bf16x8 vv = *(const bf16x8*)&Cs[row][ch * 8];
            if (which == 2) {
                const int nn = bn + half * 64 + row;      // global n (dd axis)
                const int hh = (nn >> 6) & 15, dd = nn & 63;
                const int mm = bm + ch * 8;               // tt base
                const int bb = mm >> 11, tt = mm & 2047;
                *(bf16x8*)(qkv + (size_t)2 * 4194304 +
                           (((size_t)bb * 16 + hh) * 64 + dd) * 2048 + tt) = vv;
            } else {
                const int mm = bm + half * 64 + row;      // global m (token)
                const int bb = mm >> 11, tt = mm & 2047;
                const int nn = bn + ch * 8;
                const int hh = (nn >> 6) & 15, dd = nn & 63;
                *(bf16x8*)(qkv + (size_t)which * 4194304 +
                           (((size_t)bb * 16 + hh) * 2048 + tt) * 64 + dd) = vv;
            }
        }
    }
}

// 64x128-tile fp32-output GEMM (512 blocks = 2/CU, XCD-swizzled).
// Non-temporal C stores (out is write-only).
__global__ __launch_bounds__(256) void gemm_bf16_nt_out(
    const unsigned short* __restrict__ A, const unsigned short* __restrict__ Bm,
    float* __restrict__ C, int M, int N, int K)
{
    __shared__ __align__(16) unsigned short As[64 * 32];
    __shared__ __align__(16) unsigned short Bs[128 * 32];

    const int tid  = threadIdx.x;
    const int lane = tid & 63, w = tid >> 6;

    // bijective XCD swizzle: nwg = 8*64 = 512, 64 per XCD
    const int lin = (int)(blockIdx.y * gridDim.x + blockIdx.x);
    const int swz = (lin & 7) * 64 + (lin >> 3);
    const int bx = swz & 7, by = swz >> 3;
    const int bm = by * 64, bn = bx * 128;

    const unsigned short* ga = A  + (size_t)(bm + w * 16 + (lane >> 2)) * K + (lane & 3) * 8;
    const unsigned short* gb = Bm + (size_t)(bn + w * 16 + (lane >> 2)) * K + (lane & 3) * 8;
    unsigned short* laA  = &As[w * 512];
    unsigned short* laB0 = &Bs[w * 512];
    unsigned short* laB1 = &Bs[2048 + w * 512];

    const int wr = w >> 1, wc = w & 1;
    const int fr = lane & 15, fq = lane >> 4;

    f32x4 acc[2][4] = {};

    for (int k0 = 0; k0 < K; k0 += 32) {
        GLDS16(ga + k0, laA);
        GLDS16(gb + k0, laB0);
        GLDS16(gb + k0 + (size_t)64 * K, laB1);
        __syncthreads();
        bf16x8 af[2], bfv[4];
#pragma unroll
        for (int i = 0; i < 2; ++i)
            af[i] = *(const bf16x8*)&As[(wr * 32 + i * 16 + fr) * 32 + fq * 8];
#pragma unroll
        for (int j = 0; j < 4; ++j)
            bfv[j] = *(const bf16x8*)&Bs[(wc * 64 + j * 16 + fr) * 32 + fq * 8];
#pragma unroll
        for (int i = 0; i < 2; ++i)
#pragma unroll
            for (int j = 0; j < 4; ++j)
                acc[i][j] = __builtin_amdgcn_mfma_f32_16x16x32_bf16(af[i], bfv[j], acc[i][j], 0, 0, 0);
        __syncthreads();
    }

#pragma unroll
    for (int i = 0; i < 2; ++i)
#pragma unroll
        for (int j = 0; j < 4; ++j) {
            const int mb = bm + wr * 32 + i * 16 + fq * 4;
            const int n  = bn + wc * 64 + j * 16 + fr;
#pragma unroll
            for (int r = 0; r < 4; ++r)
                __builtin_nontemporal_store(acc[i][j][r], &C[(size_t)(mb + r) * N + n]);
        }
}

// MFMA attention (round-15 form), 512 blocks x 2 sequential units.
// All 512 blocks co-resident (3 blocks/CU x 256 CU = 768 slots): no
// dispatch tail; unit-2 compute covers unit-1's store drain.
#define NT_MAX 20
__global__ __launch_bounds__(256) void attn_mfma(
    const unsigned short* __restrict__ Q, const unsigned short* __restrict__ K,
    const unsigned short* __restrict__ VT, float* __restrict__ attn,
    unsigned short* __restrict__ ao, const int* __restrict__ wptr)
{
    const int T = 2048;
    __shared__ __align__(16) unsigned short Plds[4][16][328];

    const int bid = (int)blockIdx.x;                   // 0..511
    const int g = (bid & 7) * 64 + (bid >> 3);         // XCD-contiguous
    const int w = threadIdx.x >> 6, lane = threadIdx.x & 63;
    const int fr = lane & 15, fq = lane >> 4;
    const int W2 = wptr[0] >> 1;                       // 128 (mult of 16)

    for (int uu = 0; uu < 2; ++uu) {
        const int swz = g * 2 + uu;                    // unit 0..1023
        const int tblk = swz & 31;
        const int h    = (swz >> 5) & 15;
        const int b    = swz >> 9;
        const int t0   = tblk * 64;

        const int sA = (t0 - W2) > 0 ? (t0 - W2) : 0;
        int sB = t0 + 63 + W2; if (sB > T - 1) sB = T - 1;
        const int sEnd = sB + 1;                       // 16-aligned
        const int nt  = (sEnd - sA) >> 4;              // 12..20 tiles
        const int ncc = (nt + 1) >> 1;                 // 32-wide PV chunks

        const size_t bhT = ((size_t)b * 16 + h) * T;
        const unsigned short* Qbh  = Q  + bhT * 64;
        const unsigned short* Kbh  = K  + bhT * 64;
        const unsigned short* VTbh = VT + (((size_t)b * 16 + h) * 64) * T;

        // ---- Q fragments (16 rows x 64) ----
        bf16x8 aq0 = *(const bf16x8*)(Qbh + (size_t)(t0 + w * 16 + fr) * 64 + fq * 8);
        bf16x8 aq1 = *(const bf16x8*)(Qbh + (size_t)(t0 + w * 16 + fr) * 64 + 32 + fq * 8);

        const float slope = exp2f(-0.5f * (float)(h + 1));
        const int trow0 = t0 + w * 16 + fq * 4;

        // ---- QK^T: up to 20 tiles of 16 keys ----
        f32x4 sc[NT_MAX];
#pragma unroll
        for (int st = 0; st < NT_MAX; ++st) {
            const int sbase = sA + st * 16;
            if (sbase < sEnd) {
                const unsigned short* kb = Kbh + (size_t)(sbase + fr) * 64 + fq * 8;
                bf16x8 b0 = *(const bf16x8*)(kb);
                bf16x8 b1 = *(const bf16x8*)(kb + 32);
                f32x4 sv = {0.f, 0.f, 0.f, 0.f};
                sv = __builtin_amdgcn_mfma_f32_16x16x32_bf16(aq0, b0, sv, 0, 0, 0);
                sv = __builtin_amdgcn_mfma_f32_16x16x32_bf16(aq1, b1, sv, 0, 0, 0);
                const int scol = sbase + fr;
#pragma unroll
                for (int rr = 0; rr < 4; ++rr) {
                    const int d = trow0 + rr - scol;
                    const int ad = d < 0 ? -d : d;
                    const float val = sv[rr] * 0.125f - slope * (float)ad;
                    sc[st][rr] = (ad <= W2) ? val : -1e30f;
                }
            } else {
                sc[st] = (f32x4){-1e30f, -1e30f, -1e30f, -1e30f};
            }
        }

        // ---- dependency-free zero stores (NT; drain under compute) ----
        {
            const f32x4 z4 = {0.f, 0.f, 0.f, 0.f};
            for (int i = 0; i < 16; ++i) {
                float* row = attn + (bhT + t0 + w * 16 + i) * T;
                for (int c = lane * 4; c < sA; c += 256)
                    __builtin_nontemporal_store(z4, (f32x4*)(row + c));
                for (int c = sEnd + lane * 4; c < T; c += 256)
                    __builtin_nontemporal_store(z4, (f32x4*)(row + c));
            }
        }

        // ---- softmax per row (row spread over 16 fr-lanes) ----
        float inv[4];
#pragma unroll
        for (int rr = 0; rr < 4; ++rr) {
            float m = -1e30f;
#pragma unroll
            for (int st = 0; st < NT_MAX; ++st) m = fmaxf(m, sc[st][rr]);
#pragma unroll
            for (int off = 1; off < 16; off <<= 1) m = fmaxf(m, __shfl_xor(m, off, 64));
            float s = 0.f;
#pragma unroll
            for (int st = 0; st < NT_MAX; ++st) {
                const float p = __expf(sc[st][rr] - m);
                sc[st][rr] = p;
                s += p;
            }
#pragma unroll
            for (int off = 1; off < 16; off <<= 1) s += __shfl_xor(s, off, 64);
            inv[rr] = 1.0f / s;
        }

        // ---- stage normalized probs (bf16) into per-wave LDS tile ----
#pragma unroll
        for (int st = 0; st < NT_MAX; ++st) {
            const int sbase = sA + st * 16;
            if (sbase < sEnd) {
#pragma unroll
                for (int rr = 0; rr < 4; ++rr)
                    Plds[w][fq * 4 + rr][st * 16 + fr] = f2bf(sc[st][rr] * inv[rr]);
            } else {
#pragma unroll
                for (int rr = 0; rr < 4; ++rr)
                    Plds[w][fq * 4 + rr][st * 16 + fr] = 0;
            }
        }

        // ---- in-window prob stores (ushort4 LDS read -> f32x4 NT store) ----
        for (int i = 0; i < 16; ++i) {
            float* row = attn + (bhT + t0 + w * 16 + i) * T;
            const unsigned short* prow = &Plds[w][i][0];
#pragma unroll
            for (int jj = 0; jj < 2; ++jj) {       // 2*64*4 = 512 >= 320 cols
                const int pc = (jj * 64 + lane) * 4;
                const int c = sA + pc;
                if (c < sEnd) {
                    const ushort4 p4 = *(const ushort4*)(prow + pc);
                    f32x4 v;
                    v[0] = bf2f(p4.x);
                    v[1] = bf2f(p4.y);
                    v[2] = bf2f(p4.z);
                    v[3] = bf2f(p4.w);
                    __builtin_nontemporal_store(v, (f32x4*)(row + c));
                }
            }
        }

        // ---- PV (chunk-ahead pipelined): out[16q x 64d] ----
        f32x4 oacc[4] = {};
        bf16x8 vt[4], vtn[4];
#pragma unroll
        for (int j = 0; j < 4; ++j)
            vt[j] = *(const bf16x8*)(VTbh + (size_t)(j * 16 + fr) * T + sA + fq * 8);
        for (int c = 0; c < ncc; ++c) {
            const bf16x8 pa = *(const bf16x8*)&Plds[w][fr][c * 32 + fq * 8];
            if (c + 1 < ncc) {
#pragma unroll
                for (int j = 0; j < 4; ++j)
                    vtn[j] = *(const bf16x8*)(VTbh + (size_t)(j * 16 + fr) * T + sA + (c + 1) * 32 + fq * 8);
            }
#pragma unroll
            for (int j = 0; j < 4; ++j)
                oacc[j] = __builtin_amdgcn_mfma_f32_16x16x32_bf16(pa, vt[j], oacc[j], 0, 0, 0);
#pragma unroll
            for (int j = 0; j < 4; ++j) vt[j] = vtn[j];
        }

        // ---- AO: restage 16x64 tile into dead Plds[w], vector stores ----
#pragma unroll
        for (int j = 0; j < 4; ++j)
#pragma unroll
            for (int rr = 0; rr < 4; ++rr)
                Plds[w][fq * 4 + rr][j * 16 + fr] = f2bf(oacc[j][rr]);
#pragma unroll
        for (int s = 0; s < 2; ++s) {
            const int idx = s * 64 + lane;          // 0..127
            const int row = idx >> 3;               // 0..15
            const int ch  = idx & 7;                // chunk of 8 dims
            const bf16x8 vv = *(const bf16x8*)&Plds[w][row][ch * 8];
            *(bf16x8*)(ao + ((size_t)b * T + t0 + w * 16 + row) * 1024 + h * 64 + ch * 8) = vv;
        }
    }
}

extern "C" void kernel_launch(void* const* d_in, const int* in_sizes, int n_in,
                              void* d_out, int out_size, void* d_ws, size_t ws_size,
                              hipStream_t stream)
{
    const float* x  = (const float*)d_in[0];
    const float* Wq = (const float*)d_in[1];
    const float* Wk = (const float*)d_in[2];
    const float* Wv = (const float*)d_in[3];
    const float* Wo = (const float*)d_in[4];
    const int*  win = (const int*)d_in[5];

    const int M = 4096, D = 1024;                 // M = B*T

    unsigned short* xb    = (unsigned short*)d_ws;            // 4096x1024
    unsigned short* Wqkvb = xb + (size_t)M * D;               // 3072x1024
    unsigned short* Wob   = Wqkvb + (size_t)3 * D * D;        // 1024x1024
    unsigned short* QKVb  = Wob + (size_t)D * D;              // Q,K,(V^T)
    unsigned short* AOb   = QKVb + (size_t)3 * M * D;         // 4096x1024

    float* out  = (float*)d_out;                  // (B,T,D)
    float* attn = out + (size_t)M * D;            // (B,H,T,T)

    {
        dim3 g(1024, 8);
        cast_all<<<g, 256, 0, stream>>>(x, Wq, Wk, Wv, Wo, xb, Wqkvb);
    }

    {
        dim3 g(3072 / 128, M / 128);
        gemm_bf16_nt<<<g, 256, 0, stream>>>(xb, Wqkvb, QKVb, M, 3072, D);
    }

    attn_mfma<<<512, 256, 0, stream>>>(
        QKVb, QKVb + (size_t)M * D, QKVb + (size_t)2 * M * D, attn, AOb, win);

    {
        dim3 g(D / 128, M / 64);                  // 8 x 64 = 512 blocks
        gemm_bf16_nt_out<<<g, 256, 0, stream>>>(AOb, Wob, out, M, D, D);
    }
}

// Round 20
// 192.701 us; speedup vs baseline: 1.0445x; 1.0018x over previous
//
#include <hip/hip_runtime.h>
#include <hip/hip_bf16.h>

// ---------------------------------------------------------------------------
// ALiBi MHA, windowed. B=2 T=2048 D=1024 H=16 d_k=64, window/2=128.
// Round 20 (base = round 19, 193.1us): per-unit phase reorder in attn:
// stage -> PV -> window-stores -> AO (was: stage -> window-stores -> PV ->
// AO). PV's VT loads now issue BEFORE the window stores (in-order queue:
// loads ahead of stores retire independently), so PV MFMA overlaps the
// zero-store drain and the window stores become the covered tail. AO
// restage stays last (it clobbers Plds, which window-stores read).
// ---------------------------------------------------------------------------

typedef __bf16 bf16x8 __attribute__((ext_vector_type(8)));
typedef float f32x4 __attribute__((ext_vector_type(4)));

__device__ __forceinline__ float bf2f(unsigned short u) {
    union { unsigned int i; float f; } v; v.i = ((unsigned int)u) << 16; return v.f;
}
__device__ __forceinline__ unsigned short f2bf(float f) {
    union { float f; unsigned int i; } v; v.f = f;
    unsigned int r = v.i + 0x7FFFu + ((v.i >> 16) & 1u);
    return (unsigned short)(r >> 16);
}

// slice 0..3: x (4M elems) -> xb ; slice 4..7: Wq/Wk/Wv/Wo -> wb
__global__ __launch_bounds__(256) void cast_all(
    const float* __restrict__ x,
    const float* __restrict__ wq, const float* __restrict__ wk,
    const float* __restrict__ wv, const float* __restrict__ wo,
    unsigned short* __restrict__ xb, unsigned short* __restrict__ wb)
{
    const int slice = blockIdx.y;
    const int i = (blockIdx.x * 256 + threadIdx.x) * 4;
    const float* src;
    unsigned short* dst;
    if (slice < 4) {
        src = x + (size_t)slice * 1048576;
        dst = xb + (size_t)slice * 1048576;
    } else {
        const float* ws4[4] = {wq, wk, wv, wo};
        src = ws4[slice - 4];
        dst = wb + (size_t)(slice - 4) * 1048576;
    }
    const float4 v = *(const float4*)(src + i);
    ushort4 o;
    o.x = f2bf(v.x); o.y = f2bf(v.y); o.z = f2bf(v.z); o.w = f2bf(v.w);
    *(ushort4*)(dst + i) = o;
}

#define GLDS16(g, l) __builtin_amdgcn_global_load_lds(                      \
    (const __attribute__((address_space(1))) void*)(g),                     \
    (__attribute__((address_space(3))) void*)(l), 16, 0, 0)

// QKV GEMM: C = A (MxK) * Bm^T (NxK); bf16 in, fp32 accum; bf16 out with
// V (n>=2048) transposed -> (B,H,64,T). XCD-chunk swizzled grid. Epilogue
// restages 64x128 halves of C through Cs -> 16-B vector stores only.
__global__ __launch_bounds__(256) void gemm_bf16_nt(
    const unsigned short* __restrict__ A, const unsigned short* __restrict__ Bm,
    unsigned short* __restrict__ qkv, int M, int N, int K)
{
    __shared__ __align__(16) unsigned short As[128 * 32];
    __shared__ __align__(16) unsigned short Bs[128 * 32];
    __shared__ __align__(16) unsigned short Cs[64][136];

    const int tid  = threadIdx.x;
    const int lane = tid & 63, w = tid >> 6;

    // bijective XCD-chunk swizzle: nwg = 24*32 = 768, 768/8 = 96 per XCD
    const int lin = (int)(blockIdx.y * gridDim.x + blockIdx.x);
    const int swz = (lin & 7) * 96 + (lin >> 3);
    const int bx = swz % 24, by = swz / 24;
    const int bm = by * 128, bn = bx * 128;

    const unsigned short* ga = A  + (size_t)(bm + w * 16 + (lane >> 2)) * K + (lane & 3) * 8;
    const unsigned short* gb = Bm + (size_t)(bn + w * 16 + (lane >> 2)) * K + (lane & 3) * 8;
    unsigned short* laA0 = &As[w * 512];
    unsigned short* laA1 = &As[2048 + w * 512];
    unsigned short* laB0 = &Bs[w * 512];
    unsigned short* laB1 = &Bs[2048 + w * 512];

    const int wr = w >> 1, wc = w & 1;
    const int fr = lane & 15, fq = lane >> 4;

    f32x4 acc[4][4] = {};

    for (int k0 = 0; k0 < K; k0 += 32) {
        GLDS16(ga + k0, laA0);
        GLDS16(ga + k0 + (size_t)64 * K, laA1);
        GLDS16(gb + k0, laB0);
        GLDS16(gb + k0 + (size_t)64 * K, laB1);
        __syncthreads();
        bf16x8 af[4], bfv[4];
#pragma unroll
        for (int i = 0; i < 4; ++i)
            af[i] = *(const bf16x8*)&As[(wr * 64 + i * 16 + fr) * 32 + fq * 8];
#pragma unroll
        for (int j = 0; j < 4; ++j)
            bfv[j] = *(const bf16x8*)&Bs[(wc * 64 + j * 16 + fr) * 32 + fq * 8];
#pragma unroll
        for (int i = 0; i < 4; ++i)
#pragma unroll
            for (int j = 0; j < 4; ++j)
                acc[i][j] = __builtin_amdgcn_mfma_f32_16x16x32_bf16(af[i], bfv[j], acc[i][j], 0, 0, 0);
        __syncthreads();
    }

    const int which = bn >> 10;                     // 0=Q 1=K 2=V (uniform)
#pragma unroll
    for (int half = 0; half < 2; ++half) {
        __syncthreads();
        if (which == 2) {
            if (wc == half) {
#pragma unroll
                for (int i = 0; i < 4; ++i)
#pragma unroll
                    for (int j = 0; j < 4; ++j) {
                        const int lr = wr * 64 + i * 16 + fq * 4;  // m_local
                        const int lc = j * 16 + fr;                // n within 64
#pragma unroll
                        for (int r = 0; r < 4; ++r)
                            Cs[lc][lr + r] = f2bf(acc[i][j][r]);
                    }
            }
        } else {
            if (wr == half) {
#pragma unroll
                for (int i = 0; i < 4; ++i)
#pragma unroll
                    for (int j = 0; j < 4; ++j) {
                        const int lr = i * 16 + fq * 4;            // m within 64
                        const int lc = wc * 64 + j * 16 + fr;
#pragma unroll
                        for (int r = 0; r < 4; ++r)
                            Cs[lr + r][lc] = f2bf(acc[i][j][r]);
                    }
            }
        }
        __syncthreads();
#pragma unroll
        for (int rep = 0; rep < 4; ++rep) {
            const int idx = rep * 256 + tid;
            const int row = idx >> 4;               // 0..63
            const int ch  = idx & 15;               // chunk of 8 cols
            const bf16x8 vv = *(const bf16x8*)&Cs[row][ch * 8];
            if (which == 2) {
                const int nn = bn + half * 64 + row;      // global n (dd axis)
                const int hh = (nn >> 6) & 15, dd = nn & 63;
                const int mm = bm + ch * 8;               // tt base
                const int bb = mm >> 11, tt = mm & 2047;
                *(bf16x8*)(qkv + (size_t)2 * 4194304 +
                           (((size_t)bb * 16 + hh) * 64 + dd) * 2048 + tt) = vv;
            } else {
                const int mm = bm + half * 64 + row;      // global m (token)
                const int bb = mm >> 11, tt = mm & 2047;
                const int nn = bn + ch * 8;
                const int hh = (nn >> 6) & 15, dd = nn & 63;
                *(bf16x8*)(qkv + (size_t)which * 4194304 +
                           (((size_t)bb * 16 + hh) * 2048 + tt) * 64 + dd) = vv;
            }
        }
    }
}

// 64x128-tile fp32-output GEMM (512 blocks = 2/CU, XCD-swizzled).
// Non-temporal C stores (out is write-only).
__global__ __launch_bounds__(256) void gemm_bf16_nt_out(
    const unsigned short* __restrict__ A, const unsigned short* __restrict__ Bm,
    float* __restrict__ C, int M, int N, int K)
{
    __shared__ __align__(16) unsigned short As[64 * 32];
    __shared__ __align__(16) unsigned short Bs[128 * 32];

    const int tid  = threadIdx.x;
    const int lane = tid & 63, w = tid >> 6;

    // bijective XCD swizzle: nwg = 8*64 = 512, 64 per XCD
    const int lin = (int)(blockIdx.y * gridDim.x + blockIdx.x);
    const int swz = (lin & 7) * 64 + (lin >> 3);
    const int bx = swz & 7, by = swz >> 3;
    const int bm = by * 64, bn = bx * 128;

    const unsigned short* ga = A  + (size_t)(bm + w * 16 + (lane >> 2)) * K + (lane & 3) * 8;
    const unsigned short* gb = Bm + (size_t)(bn + w * 16 + (lane >> 2)) * K + (lane & 3) * 8;
    unsigned short* laA  = &As[w * 512];
    unsigned short* laB0 = &Bs[w * 512];
    unsigned short* laB1 = &Bs[2048 + w * 512];

    const int wr = w >> 1, wc = w & 1;
    const int fr = lane & 15, fq = lane >> 4;

    f32x4 acc[2][4] = {};

    for (int k0 = 0; k0 < K; k0 += 32) {
        GLDS16(ga + k0, laA);
        GLDS16(gb + k0, laB0);
        GLDS16(gb + k0 + (size_t)64 * K, laB1);
        __syncthreads();
        bf16x8 af[2], bfv[4];
#pragma unroll
        for (int i = 0; i < 2; ++i)
            af[i] = *(const bf16x8*)&As[(wr * 32 + i * 16 + fr) * 32 + fq * 8];
#pragma unroll
        for (int j = 0; j < 4; ++j)
            bfv[j] = *(const bf16x8*)&Bs[(wc * 64 + j * 16 + fr) * 32 + fq * 8];
#pragma unroll
        for (int i = 0; i < 2; ++i)
#pragma unroll
            for (int j = 0; j < 4; ++j)
                acc[i][j] = __builtin_amdgcn_mfma_f32_16x16x32_bf16(af[i], bfv[j], acc[i][j], 0, 0, 0);
        __syncthreads();
    }

#pragma unroll
    for (int i = 0; i < 2; ++i)
#pragma unroll
        for (int j = 0; j < 4; ++j) {
            const int mb = bm + wr * 32 + i * 16 + fq * 4;
            const int n  = bn + wc * 64 + j * 16 + fr;
#pragma unroll
            for (int r = 0; r < 4; ++r)
                __builtin_nontemporal_store(acc[i][j][r], &C[(size_t)(mb + r) * N + n]);
        }
}

// MFMA attention, 512 blocks x 2 sequential units; per-unit order:
// QK^T -> zero-stores -> softmax -> stage -> PV -> window-stores -> AO.
#define NT_MAX 20
__global__ __launch_bounds__(256) void attn_mfma(
    const unsigned short* __restrict__ Q, const unsigned short* __restrict__ K,
    const unsigned short* __restrict__ VT, float* __restrict__ attn,
    unsigned short* __restrict__ ao, const int* __restrict__ wptr)
{
    const int T = 2048;
    __shared__ __align__(16) unsigned short Plds[4][16][328];

    const int bid = (int)blockIdx.x;                   // 0..511
    const int g = (bid & 7) * 64 + (bid >> 3);         // XCD-contiguous
    const int w = threadIdx.x >> 6, lane = threadIdx.x & 63;
    const int fr = lane & 15, fq = lane >> 4;
    const int W2 = wptr[0] >> 1;                       // 128 (mult of 16)

    for (int uu = 0; uu < 2; ++uu) {
        const int swz = g * 2 + uu;                    // unit 0..1023
        const int tblk = swz & 31;
        const int h    = (swz >> 5) & 15;
        const int b    = swz >> 9;
        const int t0   = tblk * 64;

        const int sA = (t0 - W2) > 0 ? (t0 - W2) : 0;
        int sB = t0 + 63 + W2; if (sB > T - 1) sB = T - 1;
        const int sEnd = sB + 1;                       // 16-aligned
        const int nt  = (sEnd - sA) >> 4;              // 12..20 tiles
        const int ncc = (nt + 1) >> 1;                 // 32-wide PV chunks

        const size_t bhT = ((size_t)b * 16 + h) * T;
        const unsigned short* Qbh  = Q  + bhT * 64;
        const unsigned short* Kbh  = K  + bhT * 64;
        const unsigned short* VTbh = VT + (((size_t)b * 16 + h) * 64) * T;

        // ---- Q fragments (16 rows x 64) ----
        bf16x8 aq0 = *(const bf16x8*)(Qbh + (size_t)(t0 + w * 16 + fr) * 64 + fq * 8);
        bf16x8 aq1 = *(const bf16x8*)(Qbh + (size_t)(t0 + w * 16 + fr) * 64 + 32 + fq * 8);

        const float slope = exp2f(-0.5f * (float)(h + 1));
        const int trow0 = t0 + w * 16 + fq * 4;

        // ---- QK^T: up to 20 tiles of 16 keys ----
        f32x4 sc[NT_MAX];
#pragma unroll
        for (int st = 0; st < NT_MAX; ++st) {
            const int sbase = sA + st * 16;
            if (sbase < sEnd) {
                const unsigned short* kb = Kbh + (size_t)(sbase + fr) * 64 + fq * 8;
                bf16x8 b0 = *(const bf16x8*)(kb);
                bf16x8 b1 = *(const bf16x8*)(kb + 32);
                f32x4 sv = {0.f, 0.f, 0.f, 0.f};
                sv = __builtin_amdgcn_mfma_f32_16x16x32_bf16(aq0, b0, sv, 0, 0, 0);
                sv = __builtin_amdgcn_mfma_f32_16x16x32_bf16(aq1, b1, sv, 0, 0, 0);
                const int scol = sbase + fr;
#pragma unroll
                for (int rr = 0; rr < 4; ++rr) {
                    const int d = trow0 + rr - scol;
                    const int ad = d < 0 ? -d : d;
                    const float val = sv[rr] * 0.125f - slope * (float)ad;
                    sc[st][rr] = (ad <= W2) ? val : -1e30f;
                }
            } else {
                sc[st] = (f32x4){-1e30f, -1e30f, -1e30f, -1e30f};
            }
        }

        // ---- dependency-free zero stores (NT; drain under compute) ----
        {
            const f32x4 z4 = {0.f, 0.f, 0.f, 0.f};
            for (int i = 0; i < 16; ++i) {
                float* row = attn + (bhT + t0 + w * 16 + i) * T;
                for (int c = lane * 4; c < sA; c += 256)
                    __builtin_nontemporal_store(z4, (f32x4*)(row + c));
                for (int c = sEnd + lane * 4; c < T; c += 256)
                    __builtin_nontemporal_store(z4, (f32x4*)(row + c));
            }
        }

        // ---- softmax per row (row spread over 16 fr-lanes) ----
        float inv[4];
#pragma unroll
        for (int rr = 0; rr < 4; ++rr) {
            float m = -1e30f;
#pragma unroll
            for (int st = 0; st < NT_MAX; ++st) m = fmaxf(m, sc[st][rr]);
#pragma unroll
            for (int off = 1; off < 16; off <<= 1) m = fmaxf(m, __shfl_xor(m, off, 64));
            float s = 0.f;
#pragma unroll
            for (int st = 0; st < NT_MAX; ++st) {
                const float p = __expf(sc[st][rr] - m);
                sc[st][rr] = p;
                s += p;
            }
#pragma unroll
            for (int off = 1; off < 16; off <<= 1) s += __shfl_xor(s, off, 64);
            inv[rr] = 1.0f / s;
        }

        // ---- stage normalized probs (bf16) into per-wave LDS tile ----
#pragma unroll
        for (int st = 0; st < NT_MAX; ++st) {
            const int sbase = sA + st * 16;
            if (sbase < sEnd) {
#pragma unroll
                for (int rr = 0; rr < 4; ++rr)
                    Plds[w][fq * 4 + rr][st * 16 + fr] = f2bf(sc[st][rr] * inv[rr]);
            } else {
#pragma unroll
                for (int rr = 0; rr < 4; ++rr)
                    Plds[w][fq * 4 + rr][st * 16 + fr] = 0;
            }
        }

        // ---- PV (chunk-ahead pipelined; VT loads issue before the window
        //      stores below -> independent of the store drain) ----
        f32x4 oacc[4] = {};
        bf16x8 vt[4], vtn[4];
#pragma unroll
        for (int j = 0; j < 4; ++j)
            vt[j] = *(const bf16x8*)(VTbh + (size_t)(j * 16 + fr) * T + sA + fq * 8);
        for (int c = 0; c < ncc; ++c) {
            const bf16x8 pa = *(const bf16x8*)&Plds[w][fr][c * 32 + fq * 8];
            if (c + 1 < ncc) {
#pragma unroll
                for (int j = 0; j < 4; ++j)
                    vtn[j] = *(const bf16x8*)(VTbh + (size_t)(j * 16 + fr) * T + sA + (c + 1) * 32 + fq * 8);
            }
#pragma unroll
            for (int j = 0; j < 4; ++j)
                oacc[j] = __builtin_amdgcn_mfma_f32_16x16x32_bf16(pa, vt[j], oacc[j], 0, 0, 0);
#pragma unroll
            for (int j = 0; j < 4; ++j) vt[j] = vtn[j];
        }

        // ---- in-window prob stores (ushort4 LDS read -> f32x4 NT store) ----
        for (int i = 0; i < 16; ++i) {
            float* row = attn + (bhT + t0 + w * 16 + i) * T;
            const unsigned short* prow = &Plds[w][i][0];
#pragma unroll
            for (int jj = 0; jj < 2; ++jj) {       // 2*64*4 = 512 >= 320 cols
                const int pc = (jj * 64 + lane) * 4;
                const int c = sA + pc;
                if (c < sEnd) {
                    const ushort4 p4 = *(const ushort4*)(prow + pc);
                    f32x4 v;
                    v[0] = bf2f(p4.x);
                    v[1] = bf2f(p4.y);
                    v[2] = bf2f(p4.z);
                    v[3] = bf2f(p4.w);
                    __builtin_nontemporal_store(v, (f32x4*)(row + c));
                }
            }
        }

        // ---- AO: restage 16x64 tile into Plds[w] (window stores done),
        //      vector stores (cached: AOb re-read by the output GEMM) ----
#pragma unroll
        for (int j = 0; j < 4; ++j)
#pragma unroll
            for (int rr = 0; rr < 4; ++rr)
                Plds[w][fq * 4 + rr][j * 16 + fr] = f2bf(oacc[j][rr]);
#pragma unroll
        for (int s = 0; s < 2; ++s) {
            const int idx = s * 64 + lane;          // 0..127
            const int row = idx >> 3;               // 0..15
            const int ch  = idx & 7;                // chunk of 8 dims
            const bf16x8 vv = *(const bf16x8*)&Plds[w][row][ch * 8];
            *(bf16x8*)(ao + ((size_t)b * T + t0 + w * 16 + row) * 1024 + h * 64 + ch * 8) = vv;
        }
    }
}

extern "C" void kernel_launch(void* const* d_in, const int* in_sizes, int n_in,
                              void* d_out, int out_size, void* d_ws, size_t ws_size,
                              hipStream_t stream)
{
    const float* x  = (const float*)d_in[0];
    const float* Wq = (const float*)d_in[1];
    const float* Wk = (const float*)d_in[2];
    const float* Wv = (const float*)d_in[3];
    const float* Wo = (const float*)d_in[4];
    const int*  win = (const int*)d_in[5];

    const int M = 4096, D = 1024;                 // M = B*T

    unsigned short* xb    = (unsigned short*)d_ws;            // 4096x1024
    unsigned short* Wqkvb = xb + (size_t)M * D;               // 3072x1024
    unsigned short* Wob   = Wqkvb + (size_t)3 * D * D;        // 1024x1024
    unsigned short* QKVb  = Wob + (size_t)D * D;              // Q,K,(V^T)
    unsigned short* AOb   = QKVb + (size_t)3 * M * D;         // 4096x1024

    float* out  = (float*)d_out;                  // (B,T,D)
    float* attn = out + (size_t)M * D;            // (B,H,T,T)

    {
        dim3 g(1024, 8);
        cast_all<<<g, 256, 0, stream>>>(x, Wq, Wk, Wv, Wo, xb, Wqkvb);
    }

    {
        dim3 g(3072 / 128, M / 128);
        gemm_bf16_nt<<<g, 256, 0, stream>>>(xb, Wqkvb, QKVb, M, 3072, D);
    }

    attn_mfma<<<512, 256, 0, stream>>>(
        QKVb, QKVb + (size_t)M * D, QKVb + (size_t)2 * M * D, attn, AOb, win);

    {
        dim3 g(D / 128, M / 64);                  // 8 x 64 = 512 blocks
        gemm_bf16_nt_out<<<g, 256, 0, stream>>>(AOb, Wob, out, M, D, D);
    }
}